// Round 7
// baseline (238.769 us; speedup 1.0000x reference)
//
#include <hip/hip_runtime.h>
#include <math.h>

#define TPB 256
#define NPTS 1024

// One Jacobi rotation on symmetric 3x3 'a' (zeroing a[P][Q]), accumulating
// eigenvectors into columns of V. All indices template-constant so the
// matrices live entirely in registers (no scratch).
template<int P, int Q, int R>
__device__ __forceinline__ void jrot(float a[3][3], float V[3][3]) {
  float apq = a[P][Q];
  if (fabsf(apq) < 1e-30f) return;
  float theta = (a[Q][Q] - a[P][P]) / (2.0f * apq);
  float t = copysignf(1.0f, theta) / (fabsf(theta) + sqrtf(theta * theta + 1.0f));
  float c = 1.0f / sqrtf(t * t + 1.0f);
  float s = t * c;
  float app = a[P][P], aqq = a[Q][Q];
  a[P][P] = app - t * apq;
  a[Q][Q] = aqq + t * apq;
  a[P][Q] = 0.0f; a[Q][P] = 0.0f;
  float arp = a[R][P], arq = a[R][Q];
  a[R][P] = c * arp - s * arq; a[P][R] = a[R][P];
  a[R][Q] = s * arp + c * arq; a[Q][R] = a[R][Q];
#pragma unroll
  for (int i = 0; i < 3; ++i) {
    float vip = V[i][P], viq = V[i][Q];
    V[i][P] = c * vip - s * viq;
    V[i][Q] = s * vip + c * viq;
  }
}

#define CSWAP(I, J)                                                        \
  if (ev[I] < ev[J]) {                                                     \
    float e_ = ev[I]; ev[I] = ev[J]; ev[J] = e_;                           \
    _Pragma("unroll")                                                      \
    for (int r2_ = 0; r2_ < 3; ++r2_) {                                    \
      float v_ = V[r2_][I]; V[r2_][I] = V[r2_][J]; V[r2_][J] = v_;         \
    }                                                                      \
  }

// From the 16 reduced sums r[] produce the 4x4 transform at 'o'.
__device__ __forceinline__ void svd_tail_write(const float r[16], float* o) {
  const float S = r[0];
  const float inv = 1.0f / (S + 1e-5f);
  const float sc[3] = {r[1] * inv, r[2] * inv, r[3] * inv};
  const float tc[3] = {r[4] * inv, r[5] * inv, r[6] * inv};
  const float f = 2.0f - S * inv;  // exact eps correction factor

  float H[3][3];
#pragma unroll
  for (int c = 0; c < 3; ++c)
#pragma unroll
    for (int d = 0; d < 3; ++d)
      H[c][d] = r[7 + 3 * c + d] * inv - sc[c] * tc[d] * f;

  // 3x3 SVD via Jacobi eigendecomposition of H^T H
  float Bm[3][3];
#pragma unroll
  for (int i = 0; i < 3; ++i)
#pragma unroll
    for (int j = 0; j < 3; ++j)
      Bm[i][j] = H[0][i] * H[0][j] + H[1][i] * H[1][j] + H[2][i] * H[2][j];

  float V[3][3] = {{1, 0, 0}, {0, 1, 0}, {0, 0, 1}};
  for (int sweep = 0; sweep < 8; ++sweep) {
    jrot<0, 1, 2>(Bm, V);
    jrot<0, 2, 1>(Bm, V);
    jrot<1, 2, 0>(Bm, V);
  }
  float ev[3] = {Bm[0][0], Bm[1][1], Bm[2][2]};
  CSWAP(0, 1)
  CSWAP(1, 2)
  CSWAP(0, 1)  // columns of V sorted by descending eigenvalue

  // U columns: U0 = H V0 / |.|, U1 = GS(H V1), U2 = U0 x U1 (det U = +1)
  float U[3][3];
  float w0[3], w1[3];
#pragma unroll
  for (int i = 0; i < 3; ++i)
    w0[i] = H[i][0] * V[0][0] + H[i][1] * V[1][0] + H[i][2] * V[2][0];
  float n0 = sqrtf(w0[0] * w0[0] + w0[1] * w0[1] + w0[2] * w0[2]);
  float in0 = (n0 > 1e-20f) ? 1.0f / n0 : 0.0f;
#pragma unroll
  for (int i = 0; i < 3; ++i) U[i][0] = w0[i] * in0;

#pragma unroll
  for (int i = 0; i < 3; ++i)
    w1[i] = H[i][0] * V[0][1] + H[i][1] * V[1][1] + H[i][2] * V[2][1];
  float d01 = U[0][0] * w1[0] + U[1][0] * w1[1] + U[2][0] * w1[2];
#pragma unroll
  for (int i = 0; i < 3; ++i) w1[i] -= d01 * U[i][0];
  float n1 = sqrtf(w1[0] * w1[0] + w1[1] * w1[1] + w1[2] * w1[2]);
  float in1 = (n1 > 1e-20f) ? 1.0f / n1 : 0.0f;
#pragma unroll
  for (int i = 0; i < 3; ++i) U[i][1] = w1[i] * in1;

  U[0][2] = U[1][0] * U[2][1] - U[2][0] * U[1][1];
  U[1][2] = U[2][0] * U[0][1] - U[0][0] * U[2][1];
  U[2][2] = U[0][0] * U[1][1] - U[1][0] * U[0][1];

  float detV = V[0][0] * (V[1][1] * V[2][2] - V[1][2] * V[2][1]) -
               V[0][1] * (V[1][0] * V[2][2] - V[1][2] * V[2][0]) +
               V[0][2] * (V[1][0] * V[2][1] - V[1][1] * V[2][0]);
  float s3 = (detV >= 0.0f) ? 1.0f : -1.0f;

  // R = V diag(1,1,s) U^T (invariant to eigencolumn sign choices)
  float R[3][3];
#pragma unroll
  for (int i = 0; i < 3; ++i)
#pragma unroll
    for (int j = 0; j < 3; ++j)
      R[i][j] = V[i][0] * U[j][0] + V[i][1] * U[j][1] + s3 * V[i][2] * U[j][2];

  float tr[3];
#pragma unroll
  for (int i = 0; i < 3; ++i)
    tr[i] = tc[i] - (R[i][0] * sc[0] + R[i][1] * sc[1] + R[i][2] * sc[2]);

  o[0] = R[0][0]; o[1] = R[0][1]; o[2]  = R[0][2]; o[3]  = tr[0];
  o[4] = R[1][0]; o[5] = R[1][1]; o[6]  = R[1][2]; o[7]  = tr[1];
  o[8] = R[2][0]; o[9] = R[2][1]; o[10] = R[2][2]; o[11] = tr[2];
  o[12] = 0.0f;   o[13] = 0.0f;   o[14] = 0.0f;    o[15] = 1.0f;
}

// Streaming reduction kernel. One block per batch; 4 consecutive points per
// thread loaded direct-to-register (no LDS staging — zero reuse exists).
// FUSED=true: thread 0 also runs the SVD (fallback if d_ws too small).
template<bool FUSED>
__global__ __launch_bounds__(TPB) void wproc_main(
    const float* __restrict__ src, const float* __restrict__ tgt,
    const float* __restrict__ wts, float* __restrict__ out,
    float* __restrict__ ws) {
  const int b = blockIdx.x;
  const int t = threadIdx.x;
  const int lane = t & 63, wave = t >> 6;

  // stride 20 floats = 80 B rows: 16B-aligned for float4 writes and
  // conflict-free (20 coprime-ish with 32) for the column reads below.
  __shared__ float sh_part[64][20];  // 5.0 KiB
  __shared__ float sh_fin[4][17];
  __shared__ float sh_r[16];

  const float4* g_src = (const float4*)(src + (size_t)b * (NPTS * 3));
  const float4* g_tgt = (const float4*)(tgt + (size_t)b * (NPTS * 3));
  const float4* g_w   = (const float4*)(wts + (size_t)b * NPTS);

  // Thread t owns points 4t..4t+3: 3 float4 = 12 floats (xyz interleaved),
  // weights are the matching float4 at index t.
  const float4 s0 = g_src[3 * t + 0], s1 = g_src[3 * t + 1], s2 = g_src[3 * t + 2];
  const float4 u0 = g_tgt[3 * t + 0], u1 = g_tgt[3 * t + 1], u2 = g_tgt[3 * t + 2];
  const float4 w4 = g_w[t];

  // acc: [0]=Sw, [1..3]=Σw*src, [4..6]=Σw*tgt, [7..15]=Σw*src⊗tgt
  float acc[16];
#pragma unroll
  for (int k = 0; k < 16; ++k) acc[k] = 0.0f;

#define PT(W, SX, SY, SZ, TX, TY, TZ)                                   \
  {                                                                     \
    float wv = fmaxf((W), 0.0f); /* WEIGHT_THRESH = 0.0 */              \
    float wsx = wv * (SX), wsy = wv * (SY), wsz = wv * (SZ);            \
    acc[0] += wv;                                                       \
    acc[1] += wsx;       acc[2] += wsy;       acc[3] += wsz;            \
    acc[4] += wv * (TX); acc[5] += wv * (TY); acc[6] += wv * (TZ);      \
    acc[7]  += wsx * (TX); acc[8]  += wsx * (TY); acc[9]  += wsx * (TZ);\
    acc[10] += wsy * (TX); acc[11] += wsy * (TY); acc[12] += wsy * (TZ);\
    acc[13] += wsz * (TX); acc[14] += wsz * (TY); acc[15] += wsz * (TZ);\
  }

  PT(w4.x, s0.x, s0.y, s0.z, u0.x, u0.y, u0.z)
  PT(w4.y, s0.w, s1.x, s1.y, u0.w, u1.x, u1.y)
  PT(w4.z, s1.z, s1.w, s2.x, u1.z, u1.w, u2.x)
  PT(w4.w, s2.y, s2.z, s2.w, u2.y, u2.z, u2.w)
#undef PT

  // Two butterfly steps only (32 shuffles instead of 96), then LDS transpose.
#pragma unroll
  for (int k = 0; k < 16; ++k) acc[k] += __shfl_down(acc[k], 32, 64);
#pragma unroll
  for (int k = 0; k < 16; ++k) acc[k] += __shfl_down(acc[k], 16, 64);

  if (lane < 16) {  // lanes 0..15 hold sums over their 4-lane comb
    float4* pr = (float4*)&sh_part[wave * 16 + lane][0];
    pr[0] = make_float4(acc[0], acc[1], acc[2], acc[3]);
    pr[1] = make_float4(acc[4], acc[5], acc[6], acc[7]);
    pr[2] = make_float4(acc[8], acc[9], acc[10], acc[11]);
    pr[3] = make_float4(acc[12], acc[13], acc[14], acc[15]);
  }
  __syncthreads();

  // 64 threads: thread (g,k) sums component k over rows g*16..g*16+15.
  if (t < 64) {
    const int k = t & 15, g = t >> 4;
    float s = 0.0f;
#pragma unroll
    for (int j = 0; j < 16; ++j) s += sh_part[g * 16 + j][k];
    sh_fin[g][k] = s;
  }
  __syncthreads();

  if (t < 16) {
    float rk = sh_fin[0][t] + sh_fin[1][t] + sh_fin[2][t] + sh_fin[3][t];
    if constexpr (FUSED) sh_r[t] = rk;
    else ws[(size_t)b * 16 + t] = rk;
  }

  if constexpr (FUSED) {
    __syncthreads();
    if (t != 0) return;
    float r[16];
#pragma unroll
    for (int k = 0; k < 16; ++k) r[k] = sh_r[k];
    svd_tail_write(r, out + (size_t)b * 16);
  }
}

// One thread per batch: 8192-way parallel 3x3 SVD + transform assembly.
__global__ __launch_bounds__(TPB) void wproc_svd(
    const float* __restrict__ ws, float* __restrict__ out, int B) {
  const int i = blockIdx.x * TPB + threadIdx.x;
  if (i >= B) return;
  const float4* p = (const float4*)(ws + (size_t)i * 16);
  const float4 a = p[0], bq = p[1], c = p[2], d = p[3];
  const float r[16] = {a.x,  a.y,  a.z,  a.w,  bq.x, bq.y, bq.z, bq.w,
                       c.x,  c.y,  c.z,  c.w,  d.x,  d.y,  d.z,  d.w};
  svd_tail_write(r, out + (size_t)i * 16);
}

extern "C" void kernel_launch(void* const* d_in, const int* in_sizes, int n_in,
                              void* d_out, int out_size, void* d_ws, size_t ws_size,
                              hipStream_t stream) {
  const float* src = (const float*)d_in[0];
  const float* tgt = (const float*)d_in[1];
  const float* wts = (const float*)d_in[2];
  float* out = (float*)d_out;
  const int B = in_sizes[0] / (NPTS * 3);
  const size_t need = (size_t)B * 16 * sizeof(float);
  if (ws_size >= need) {
    // Split path: streaming kernel stays low-VGPR / high-occupancy,
    // SVDs run fully parallel (one thread per batch) in a ~2 us kernel.
    wproc_main<false><<<dim3(B), dim3(TPB), 0, stream>>>(src, tgt, wts, out,
                                                         (float*)d_ws);
    wproc_svd<<<dim3((B + TPB - 1) / TPB), dim3(TPB), 0, stream>>>(
        (const float*)d_ws, out, B);
  } else {
    wproc_main<true><<<dim3(B), dim3(TPB), 0, stream>>>(src, tgt, wts, out,
                                                        nullptr);
  }
}